// Round 1
// baseline (469.976 us; speedup 1.0000x reference)
//
#include <hip/hip_runtime.h>

#define Bn 2
#define Tn 2048
#define Cn 1024
#define NHn 16

typedef __attribute__((ext_vector_type(8))) short s16x8;
typedef __attribute__((ext_vector_type(4))) float f32x4;
typedef __attribute__((ext_vector_type(8))) unsigned short u16x8;
typedef __attribute__((ext_vector_type(4))) unsigned short u16x4;
typedef const __attribute__((address_space(1))) void* gas_t;
typedef __attribute__((address_space(3))) void* las_t;

__device__ __forceinline__ void gl_lds16(const void* g, void* l) {
  __builtin_amdgcn_global_load_lds((gas_t)g, (las_t)l, 16, 0, 0);
}

__device__ __forceinline__ float bf2f(unsigned short u) {
  unsigned int x = ((unsigned int)u) << 16;
  float f; __builtin_memcpy(&f, &x, 4); return f;
}
__device__ __forceinline__ unsigned short f2bf(float f) {
  unsigned int x; __builtin_memcpy(&x, &f, 4);
  x += 0x7fffu + ((x >> 16) & 1u);
  return (unsigned short)(x >> 16);
}
__device__ __forceinline__ float selu_f(float x) {
  const float SC = 1.0507009873554805f, AL = 1.6732632423543772f;
  return x > 0.f ? SC * x : SC * AL * (__expf(x) - 1.f);
}
__device__ __forceinline__ float waveRS(float v) {
#pragma unroll
  for (int m = 32; m; m >>= 1) v += __shfl_xor(v, m, 64);
  return v;
}

// ---------------- cast f32 -> bf16 (weights) ----------------
__global__ __launch_bounds__(256) void cast_f32_bf16(
    const float* __restrict__ in, unsigned short* __restrict__ out) {
  size_t i = ((size_t)blockIdx.x * 256 + threadIdx.x) * 4;
  float4 v = *(const float4*)(in + i);
  u16x4 o;
  o.x = f2bf(v.x); o.y = f2bf(v.y); o.z = f2bf(v.z); o.w = f2bf(v.w);
  *(u16x4*)(out + i) = o;
}

// ---------------- modulation: cm = selu(c) @ ada_w.T + ada_b ----------------
__global__ __launch_bounds__(256) void modulation(
    const float* __restrict__ cin, const float* __restrict__ ada_w,
    const float* __restrict__ ada_b, float* __restrict__ cm) {
  const int tid = threadIdx.x;
  const int w = tid >> 6, l = tid & 63;
  const int rowg = blockIdx.x * 4 + w;          // 0..12287
  const int b = rowg / 6144, j = rowg % 6144;
  __shared__ float sc[1024];
#pragma unroll
  for (int i = 0; i < 4; ++i) {
    int idx = i * 256 + tid;
    sc[idx] = selu_f(cin[b * 1024 + idx]);
  }
  __syncthreads();
  const float* wr_ = ada_w + (size_t)j * 1024;
  float acc = 0.f;
#pragma unroll
  for (int i = 0; i < 4; ++i) {
    float4 wv = *(const float4*)(wr_ + (i * 64 + l) * 4);
    const float* sp = sc + (i * 64 + l) * 4;
    acc += wv.x * sp[0] + wv.y * sp[1] + wv.z * sp[2] + wv.w * sp[3];
  }
  acc = waveRS(acc);
  if (l == 0) cm[(size_t)b * 6144 + j] = acc + ada_b[j];
}

// ---------------- LN + AdaLN modulate -> bf16 ----------------
__global__ __launch_bounds__(256) void ln_mod(
    const float* __restrict__ xin, const float* __restrict__ cm,
    unsigned short* __restrict__ hout, int shift_off, int scale_off) {
  const int tid = threadIdx.x;
  const int row = blockIdx.x;
  const int b = row >> 11;
  const float* xr = xin + (size_t)row * 1024;
  float v[4]; float s = 0.f, s2 = 0.f;
#pragma unroll
  for (int i = 0; i < 4; ++i) {
    v[i] = xr[i * 256 + tid]; s += v[i]; s2 += v[i] * v[i];
  }
  __shared__ float rs[8];
  s = waveRS(s); s2 = waveRS(s2);
  const int w = tid >> 6, l = tid & 63;
  if (l == 0) { rs[w] = s; rs[4 + w] = s2; }
  __syncthreads();
  s = rs[0] + rs[1] + rs[2] + rs[3];
  s2 = rs[4] + rs[5] + rs[6] + rs[7];
  float mean = s * (1.f / 1024.f);
  float var = s2 * (1.f / 1024.f) - mean * mean;
  float rstd = rsqrtf(var + 1e-6f);
  const float* cb = cm + b * 6144;
#pragma unroll
  for (int i = 0; i < 4; ++i) {
    int ch = i * 256 + tid;
    float hv = (v[i] - mean) * rstd * (1.f + cb[scale_off + ch]) + cb[shift_off + ch];
    hout[(size_t)row * 1024 + ch] = f2bf(hv);
  }
}

// ---------------- GEMM: out[M][N] = A[M][K](bf16) * Bw[N][K](bf16)^T ----------------
// MODE 0: +bias -> bf16 ; MODE 1: selu(+bias) -> bf16 ; MODE 2: x2 + gate_f*(+bias) -> f32
template <int MODE>
__global__ __launch_bounds__(256) void gemm_bt(
    const unsigned short* __restrict__ A, const unsigned short* __restrict__ Bw,
    const float* __restrict__ bias, unsigned short* __restrict__ obf,
    float* __restrict__ of32, const float* __restrict__ resid,
    const float* __restrict__ cm, int M, int N, int K) {
  __shared__ unsigned short As[128 * 32];
  __shared__ unsigned short Bs[128 * 32];
  const int tid = threadIdx.x;
  const int bm = blockIdx.y, bn = blockIdx.x;
  const int w = tid >> 6, l = tid & 63;
  const int wr = w >> 1, wc = w & 1;
  const int lr = l & 15, lg = l >> 4;

  f32x4 acc[4][4];
#pragma unroll
  for (int m = 0; m < 4; ++m)
#pragma unroll
    for (int n = 0; n < 4; ++n) acc[m][n] = (f32x4){0.f, 0.f, 0.f, 0.f};

  const int c0 = tid, c1 = tid + 256;
  const size_t a0 = (size_t)(bm * 128 + (c0 >> 2)) * K + (c0 & 3) * 8;
  const size_t a1 = (size_t)(bm * 128 + (c1 >> 2)) * K + (c1 & 3) * 8;
  const size_t b0 = (size_t)(bn * 128 + (c0 >> 2)) * K + (c0 & 3) * 8;
  const size_t b1 = (size_t)(bn * 128 + (c1 >> 2)) * K + (c1 & 3) * 8;
  const int nkt = K >> 5;
  for (int kt = 0; kt < nkt; ++kt) {
    const int ko = kt * 32;
    __syncthreads();
    gl_lds16(A + a0 + ko, As + c0 * 8);
    gl_lds16(A + a1 + ko, As + c1 * 8);
    gl_lds16(Bw + b0 + ko, Bs + c0 * 8);
    gl_lds16(Bw + b1 + ko, Bs + c1 * 8);
    __syncthreads();
    s16x8 af[4], bf[4];
#pragma unroll
    for (int m = 0; m < 4; ++m)
      af[m] = *(const s16x8*)(As + (wr * 64 + m * 16 + lr) * 32 + lg * 8);
#pragma unroll
    for (int n = 0; n < 4; ++n)
      bf[n] = *(const s16x8*)(Bs + (wc * 64 + n * 16 + lr) * 32 + lg * 8);
#pragma unroll
    for (int m = 0; m < 4; ++m)
#pragma unroll
      for (int n = 0; n < 4; ++n)
        acc[m][n] = __builtin_amdgcn_mfma_f32_16x16x32_bf16(af[m], bf[n], acc[m][n], 0, 0, 0);
  }
#pragma unroll
  for (int m = 0; m < 4; ++m) {
#pragma unroll
    for (int n = 0; n < 4; ++n) {
      const int col = bn * 128 + wc * 64 + n * 16 + lr;
      const float bv = bias[col];
#pragma unroll
      for (int r = 0; r < 4; ++r) {
        const int row = bm * 128 + wr * 64 + m * 16 + lg * 4 + r;
        float v = acc[m][n][r] + bv;
        if (MODE == 0) {
          obf[(size_t)row * N + col] = f2bf(v);
        } else if (MODE == 1) {
          obf[(size_t)row * N + col] = f2bf(selu_f(v));
        } else {
          const int b = row >> 11;
          const float g = cm[b * 6144 + 5 * 1024 + col];
          of32[(size_t)row * N + col] = resid[(size_t)row * N + col] + g * v;
        }
      }
    }
  }
}

// ---------------- RoPE + repack: qkv -> Q[bh][t][d], K[bh][t][d], Vt[bh][d][t] ----------------
__global__ __launch_bounds__(256) void rope_pack(
    const unsigned short* __restrict__ qkv, const float* __restrict__ cosp,
    const float* __restrict__ sinp, const float* __restrict__ scalep,
    unsigned short* __restrict__ Qo, unsigned short* __restrict__ Ko,
    unsigned short* __restrict__ Vt) {
  const int tid = threadIdx.x;
  const int blk = blockIdx.x;
  const int tt = blk & 31, bh = blk >> 5;
  const int b = bh >> 4, h = bh & 15;
  const int t0 = tt * 64;
  __shared__ __align__(16) unsigned short tile[64][192];  // [t][q0..63|k64..127|v128..191]
#pragma unroll
  for (int i = 0; i < 6; ++i) {
    int cidx = i * 256 + tid;
    int r = cidx / 24, sg = cidx % 24;
    int colbase = (sg < 8) ? (h * 64 + sg * 8)
                : (sg < 16) ? (Cn + h * 64 + (sg - 8) * 8)
                            : (2 * Cn + h * 64 + (sg - 16) * 8);
    u16x8 v = *(const u16x8*)(qkv + (size_t)(b * Tn + t0 + r) * 3072 + colbase);
    *(u16x8*)(&tile[r][sg * 8]) = v;
  }
  __syncthreads();
  {
    const int t = tid >> 2, d0 = (tid & 3) * 16;
    const int tg = t0 + t;
    float co[16], si[16], sc[16];
#pragma unroll
    for (int i = 0; i < 4; ++i) {
      *(float4*)(co + i * 4) = *(const float4*)(cosp + (size_t)tg * 64 + d0 + i * 4);
      *(float4*)(si + i * 4) = *(const float4*)(sinp + (size_t)tg * 64 + d0 + i * 4);
      *(float4*)(sc + i * 4) = *(const float4*)(scalep + (size_t)tg * 64 + d0 + i * 4);
    }
    u16x8 qv[2], kv[2];
    unsigned short* qo = (unsigned short*)qv;
    unsigned short* ko = (unsigned short*)kv;
#pragma unroll
    for (int i = 0; i < 8; ++i) {
      int d = 2 * i;
      float q0 = bf2f(tile[t][d0 + d]), q1 = bf2f(tile[t][d0 + d + 1]);
      float k0 = bf2f(tile[t][64 + d0 + d]), k1 = bf2f(tile[t][64 + d0 + d + 1]);
      float qr0 = (q0 * co[d] - q1 * si[d]) * sc[d];
      float qr1 = (q1 * co[d + 1] + q0 * si[d + 1]) * sc[d + 1];
      float kr0 = (k0 * co[d] - k1 * si[d]) / sc[d];
      float kr1 = (k1 * co[d + 1] + k0 * si[d + 1]) / sc[d + 1];
      qo[d] = f2bf(qr0); qo[d + 1] = f2bf(qr1);
      ko[d] = f2bf(kr0); ko[d + 1] = f2bf(kr1);
    }
    size_t obase = ((size_t)bh * Tn + tg) * 64 + d0;
    *(u16x8*)(Qo + obase) = qv[0];
    *(u16x8*)(Qo + obase + 8) = qv[1];
    *(u16x8*)(Ko + obase) = kv[0];
    *(u16x8*)(Ko + obase + 8) = kv[1];
  }
  {
    const int d = tid >> 2, ts = (tid & 3) * 16;
    u16x8 vv[2];
    unsigned short* vp = (unsigned short*)vv;
#pragma unroll
    for (int j = 0; j < 16; ++j) vp[j] = tile[ts + j][128 + d];
    size_t obase = ((size_t)bh * 64 + d) * Tn + t0 + ts;
    *(u16x8*)(Vt + obase) = vv[0];
    *(u16x8*)(Vt + obase + 8) = vv[1];
  }
}

// ---------------- causal flash attention + fused residual: x2 = x + gate*attn ----------------
__global__ __launch_bounds__(256) void attn_kernel(
    const unsigned short* __restrict__ Q, const unsigned short* __restrict__ Kb,
    const unsigned short* __restrict__ Vt, const float* __restrict__ x,
    const float* __restrict__ cm, float* __restrict__ x2) {
  const int bh = blockIdx.y;
  const int b = bh >> 4, h = bh & 15;
  const int tid = threadIdx.x;
  const int w = tid >> 6, l = tid & 63;
  const int lr = l & 15, lg = l >> 4;
  const int q0 = blockIdx.x * 64 + w * 16;
  const float inv_tp = 0.08838834764831845f;  // 1/sqrt(2*64)

  const unsigned short* Qp = Q + ((size_t)bh * Tn + q0) * 64;
  s16x8 qa0 = *(const s16x8*)(Qp + lr * 64 + lg * 8);
  s16x8 qa1 = *(const s16x8*)(Qp + lr * 64 + 32 + lg * 8);

  f32x4 o[4];
#pragma unroll
  for (int c = 0; c < 4; ++c) o[c] = (f32x4){0.f, 0.f, 0.f, 0.f};
  float mrow[4] = {-1e30f, -1e30f, -1e30f, -1e30f};
  float lsum[4] = {0.f, 0.f, 0.f, 0.f};

  __shared__ __align__(16) unsigned short P[4][16][40];  // per-wave P tile [q][key]
  unsigned short(*Pw)[40] = P[w];

  const unsigned short* Kbase = Kb + (size_t)bh * Tn * 64;
  const unsigned short* Vbase = Vt + (size_t)bh * 64 * Tn;
  const int ntiles = (q0 + 47) >> 5;
  for (int kt = 0; kt < ntiles; ++kt) {
    const int kb = kt * 32;
    f32x4 s[2];
#pragma unroll
    for (int cc = 0; cc < 2; ++cc) {
      const unsigned short* Kp = Kbase + (size_t)(kb + cc * 16 + lr) * 64 + lg * 8;
      s16x8 k0 = *(const s16x8*)(Kp);
      s16x8 k1 = *(const s16x8*)(Kp + 32);
      f32x4 t = (f32x4){0.f, 0.f, 0.f, 0.f};
      t = __builtin_amdgcn_mfma_f32_16x16x32_bf16(qa0, k0, t, 0, 0, 0);
      t = __builtin_amdgcn_mfma_f32_16x16x32_bf16(qa1, k1, t, 0, 0, 0);
      s[cc] = t;
    }
    float tmax[4];
#pragma unroll
    for (int r = 0; r < 4; ++r) {
      const int q = q0 + lg * 4 + r;
      float s0 = s[0][r] * inv_tp; if (kb + lr > q) s0 = -1e30f;
      float s1 = s[1][r] * inv_tp; if (kb + 16 + lr > q) s1 = -1e30f;
      s[0][r] = s0; s[1][r] = s1;
      tmax[r] = fmaxf(s0, s1);
    }
#pragma unroll
    for (int d = 1; d < 16; d <<= 1)
#pragma unroll
      for (int r = 0; r < 4; ++r) tmax[r] = fmaxf(tmax[r], __shfl_xor(tmax[r], d, 64));
#pragma unroll
    for (int r = 0; r < 4; ++r) {
      float mn = fmaxf(mrow[r], tmax[r]);
      float alpha = __expf(mrow[r] - mn);
      mrow[r] = mn;
      float p0 = __expf(s[0][r] - mn);
      float p1 = __expf(s[1][r] - mn);
      lsum[r] = lsum[r] * alpha + p0 + p1;
      Pw[lg * 4 + r][lr] = f2bf(p0);
      Pw[lg * 4 + r][16 + lr] = f2bf(p1);
#pragma unroll
      for (int c = 0; c < 4; ++c) o[c][r] *= alpha;
    }
    asm volatile("s_waitcnt lgkmcnt(0)" ::: "memory");
    s16x8 pa = *(const s16x8*)(&Pw[lr][lg * 8]);
#pragma unroll
    for (int c = 0; c < 4; ++c) {
      s16x8 vb = *(const s16x8*)(Vbase + (size_t)(c * 16 + lr) * Tn + kb + lg * 8);
      o[c] = __builtin_amdgcn_mfma_f32_16x16x32_bf16(pa, vb, o[c], 0, 0, 0);
    }
  }
#pragma unroll
  for (int d = 1; d < 16; d <<= 1)
#pragma unroll
    for (int r = 0; r < 4; ++r) lsum[r] += __shfl_xor(lsum[r], d, 64);
#pragma unroll
  for (int c = 0; c < 4; ++c) {
#pragma unroll
    for (int r = 0; r < 4; ++r) {
      const int q = q0 + lg * 4 + r;
      const int col = h * 64 + c * 16 + lr;
      const size_t idx = ((size_t)b * Tn + q) * Cn + col;
      float val = o[c][r] / lsum[r];
      x2[idx] = x[idx] + cm[b * 6144 + 2048 + col] * val;
    }
  }
}

// ---------------- launch ----------------
extern "C" void kernel_launch(void* const* d_in, const int* in_sizes, int n_in,
                              void* d_out, int out_size, void* d_ws, size_t ws_size,
                              hipStream_t stream) {
  (void)in_sizes; (void)n_in; (void)out_size; (void)ws_size;
  const float* x = (const float*)d_in[0];
  const float* pe_cos = (const float*)d_in[1];
  const float* pe_sin = (const float*)d_in[2];
  const float* pe_scale = (const float*)d_in[3];
  const float* cc = (const float*)d_in[4];
  // d_in[5] = mask: causal, computed analytically
  const float* qkv_w = (const float*)d_in[6];
  const float* qkv_b = (const float*)d_in[7];
  const float* w1 = (const float*)d_in[8];
  const float* b1 = (const float*)d_in[9];
  const float* w2 = (const float*)d_in[10];
  const float* b2 = (const float*)d_in[11];
  const float* ada_w = (const float*)d_in[12];
  const float* ada_b = (const float*)d_in[13];
  float* out = (float*)d_out;
  char* ws = (char*)d_ws;

  unsigned short* qkvw_bf = (unsigned short*)(ws + 0);
  unsigned short* w1_bf = (unsigned short*)(ws + 6291456);
  unsigned short* w2_bf = (unsigned short*)(ws + 14680064);
  float* cm = (float*)(ws + 23068672);
  unsigned short* h1 = (unsigned short*)(ws + 23117824);   // reused as h2
  unsigned short* qkvb = (unsigned short*)(ws + 31506432); // reused (+Q) as ff1
  unsigned short* Qb = (unsigned short*)(ws + 56672256);
  unsigned short* Kb2 = (unsigned short*)(ws + 65060864);
  unsigned short* Vtb = (unsigned short*)(ws + 73449472);
  float* x2b = (float*)(ws + 81838080);
  unsigned short* ff1b = (unsigned short*)(ws + 31506432);
  // total ws use: 98,615,296 bytes

  cast_f32_bf16<<<3072, 256, 0, stream>>>(qkv_w, qkvw_bf);
  cast_f32_bf16<<<4096, 256, 0, stream>>>(w1, w1_bf);
  cast_f32_bf16<<<4096, 256, 0, stream>>>(w2, w2_bf);
  modulation<<<3072, 256, 0, stream>>>(cc, ada_w, ada_b, cm);
  ln_mod<<<4096, 256, 0, stream>>>(x, cm, h1, 0, 1024);
  gemm_bt<0><<<dim3(24, 32), 256, 0, stream>>>(h1, qkvw_bf, qkv_b, qkvb, nullptr, nullptr, nullptr, 4096, 3072, 1024);
  rope_pack<<<1024, 256, 0, stream>>>(qkvb, pe_cos, pe_sin, pe_scale, Qb, Kb2, Vtb);
  attn_kernel<<<dim3(32, 32), 256, 0, stream>>>(Qb, Kb2, Vtb, x, cm, x2b);
  ln_mod<<<4096, 256, 0, stream>>>(x2b, cm, h1, 3072, 4096);
  gemm_bt<1><<<dim3(32, 32), 256, 0, stream>>>(h1, w1_bf, b1, ff1b, nullptr, nullptr, nullptr, 4096, 4096, 1024);
  gemm_bt<2><<<dim3(8, 32), 256, 0, stream>>>(ff1b, w2_bf, b2, nullptr, out, x2b, cm, 4096, 1024, 4096);
}

// Round 2
// 417.247 us; speedup vs baseline: 1.1264x; 1.1264x over previous
//
#include <hip/hip_runtime.h>

#define Bn 2
#define Tn 2048
#define Cn 1024
#define NHn 16

typedef __attribute__((ext_vector_type(8))) short s16x8;
typedef __attribute__((ext_vector_type(4))) short s16x4;
typedef __attribute__((ext_vector_type(4))) float f32x4;
typedef __attribute__((ext_vector_type(8))) unsigned short u16x8;
typedef __attribute__((ext_vector_type(4))) unsigned short u16x4;
typedef const __attribute__((address_space(1))) void* gas_t;
typedef __attribute__((address_space(3))) void* las_t;

#if defined(__has_builtin)
#if __has_builtin(__builtin_amdgcn_mfma_f32_16x16x16bf16_1k)
#define HAVE_MFMA16 1
#endif
#endif

__device__ __forceinline__ void gl_lds16(const void* g, void* l) {
  __builtin_amdgcn_global_load_lds((gas_t)g, (las_t)l, 16, 0, 0);
}

__device__ __forceinline__ float bf2f(unsigned short u) {
  unsigned int x = ((unsigned int)u) << 16;
  float f; __builtin_memcpy(&f, &x, 4); return f;
}
__device__ __forceinline__ unsigned short f2bf(float f) {
  unsigned int x; __builtin_memcpy(&x, &f, 4);
  x += 0x7fffu + ((x >> 16) & 1u);
  return (unsigned short)(x >> 16);
}
__device__ __forceinline__ unsigned int cvt_pk_bf16(float a, float b) {
  unsigned int r;
  asm("v_cvt_pk_bf16_f32 %0, %1, %2" : "=v"(r) : "v"(a), "v"(b));
  return r;
}
__device__ __forceinline__ float selu_f(float x) {
  const float SC = 1.0507009873554805f, AL = 1.6732632423543772f;
  return x > 0.f ? SC * x : SC * AL * (__expf(x) - 1.f);
}
__device__ __forceinline__ float waveRS(float v) {
#pragma unroll
  for (int m = 32; m; m >>= 1) v += __shfl_xor(v, m, 64);
  return v;
}

// ---------------- cast f32 -> bf16 (weights) ----------------
__global__ __launch_bounds__(256) void cast_f32_bf16(
    const float* __restrict__ in, unsigned short* __restrict__ out) {
  size_t i = ((size_t)blockIdx.x * 256 + threadIdx.x) * 4;
  float4 v = *(const float4*)(in + i);
  u16x4 o;
  o.x = f2bf(v.x); o.y = f2bf(v.y); o.z = f2bf(v.z); o.w = f2bf(v.w);
  *(u16x4*)(out + i) = o;
}

// ---------------- modulation: cm = selu(c) @ ada_w.T + ada_b ----------------
__global__ __launch_bounds__(256) void modulation(
    const float* __restrict__ cin, const float* __restrict__ ada_w,
    const float* __restrict__ ada_b, float* __restrict__ cm) {
  const int tid = threadIdx.x;
  const int w = tid >> 6, l = tid & 63;
  const int rowg = blockIdx.x * 4 + w;          // 0..12287
  const int b = rowg / 6144, j = rowg % 6144;
  __shared__ float sc[1024];
#pragma unroll
  for (int i = 0; i < 4; ++i) {
    int idx = i * 256 + tid;
    sc[idx] = selu_f(cin[b * 1024 + idx]);
  }
  __syncthreads();
  const float* wr_ = ada_w + (size_t)j * 1024;
  float acc = 0.f;
#pragma unroll
  for (int i = 0; i < 4; ++i) {
    float4 wv = *(const float4*)(wr_ + (i * 64 + l) * 4);
    const float* sp = sc + (i * 64 + l) * 4;
    acc += wv.x * sp[0] + wv.y * sp[1] + wv.z * sp[2] + wv.w * sp[3];
  }
  acc = waveRS(acc);
  if (l == 0) cm[(size_t)b * 6144 + j] = acc + ada_b[j];
}

// ---------------- LN + AdaLN modulate -> bf16 ----------------
__global__ __launch_bounds__(256) void ln_mod(
    const float* __restrict__ xin, const float* __restrict__ cm,
    unsigned short* __restrict__ hout, int shift_off, int scale_off) {
  const int tid = threadIdx.x;
  const int row = blockIdx.x;
  const int b = row >> 11;
  const float* xr = xin + (size_t)row * 1024;
  float v[4]; float s = 0.f, s2 = 0.f;
#pragma unroll
  for (int i = 0; i < 4; ++i) {
    v[i] = xr[i * 256 + tid]; s += v[i]; s2 += v[i] * v[i];
  }
  __shared__ float rs[8];
  s = waveRS(s); s2 = waveRS(s2);
  const int w = tid >> 6, l = tid & 63;
  if (l == 0) { rs[w] = s; rs[4 + w] = s2; }
  __syncthreads();
  s = rs[0] + rs[1] + rs[2] + rs[3];
  s2 = rs[4] + rs[5] + rs[6] + rs[7];
  float mean = s * (1.f / 1024.f);
  float var = s2 * (1.f / 1024.f) - mean * mean;
  float rstd = rsqrtf(var + 1e-6f);
  const float* cb = cm + b * 6144;
#pragma unroll
  for (int i = 0; i < 4; ++i) {
    int ch = i * 256 + tid;
    float hv = (v[i] - mean) * rstd * (1.f + cb[scale_off + ch]) + cb[shift_off + ch];
    hout[(size_t)row * 1024 + ch] = f2bf(hv);
  }
}

// ---------------- GEMM: out[M][N] = A[M][K](bf16) * Bw[N][K](bf16)^T ----------------
// MODE 0: +bias -> bf16 ; MODE 1: selu(+bias) -> bf16 ; MODE 2: x2 + gate_f*(+bias) -> f32
template <int MODE>
__global__ __launch_bounds__(256) void gemm_bt(
    const unsigned short* __restrict__ A, const unsigned short* __restrict__ Bw,
    const float* __restrict__ bias, unsigned short* __restrict__ obf,
    float* __restrict__ of32, const float* __restrict__ resid,
    const float* __restrict__ cm, int M, int N, int K) {
  __shared__ unsigned short As[128 * 32];
  __shared__ unsigned short Bs[128 * 32];
  const int tid = threadIdx.x;
  const int bm = blockIdx.y, bn = blockIdx.x;
  const int w = tid >> 6, l = tid & 63;
  const int wr = w >> 1, wc = w & 1;
  const int lr = l & 15, lg = l >> 4;

  f32x4 acc[4][4];
#pragma unroll
  for (int m = 0; m < 4; ++m)
#pragma unroll
    for (int n = 0; n < 4; ++n) acc[m][n] = (f32x4){0.f, 0.f, 0.f, 0.f};

  const int c0 = tid, c1 = tid + 256;
  const size_t a0 = (size_t)(bm * 128 + (c0 >> 2)) * K + (c0 & 3) * 8;
  const size_t a1 = (size_t)(bm * 128 + (c1 >> 2)) * K + (c1 & 3) * 8;
  const size_t b0 = (size_t)(bn * 128 + (c0 >> 2)) * K + (c0 & 3) * 8;
  const size_t b1 = (size_t)(bn * 128 + (c1 >> 2)) * K + (c1 & 3) * 8;
  const int nkt = K >> 5;
  for (int kt = 0; kt < nkt; ++kt) {
    const int ko = kt * 32;
    __syncthreads();
    gl_lds16(A + a0 + ko, As + c0 * 8);
    gl_lds16(A + a1 + ko, As + c1 * 8);
    gl_lds16(Bw + b0 + ko, Bs + c0 * 8);
    gl_lds16(Bw + b1 + ko, Bs + c1 * 8);
    __syncthreads();
    s16x8 af[4], bf[4];
#pragma unroll
    for (int m = 0; m < 4; ++m)
      af[m] = *(const s16x8*)(As + (wr * 64 + m * 16 + lr) * 32 + lg * 8);
#pragma unroll
    for (int n = 0; n < 4; ++n)
      bf[n] = *(const s16x8*)(Bs + (wc * 64 + n * 16 + lr) * 32 + lg * 8);
#pragma unroll
    for (int m = 0; m < 4; ++m)
#pragma unroll
      for (int n = 0; n < 4; ++n)
        acc[m][n] = __builtin_amdgcn_mfma_f32_16x16x32_bf16(af[m], bf[n], acc[m][n], 0, 0, 0);
  }
#pragma unroll
  for (int m = 0; m < 4; ++m) {
#pragma unroll
    for (int n = 0; n < 4; ++n) {
      const int col = bn * 128 + wc * 64 + n * 16 + lr;
      const float bv = bias[col];
#pragma unroll
      for (int r = 0; r < 4; ++r) {
        const int row = bm * 128 + wr * 64 + m * 16 + lg * 4 + r;
        float v = acc[m][n][r] + bv;
        if (MODE == 0) {
          obf[(size_t)row * N + col] = f2bf(v);
        } else if (MODE == 1) {
          obf[(size_t)row * N + col] = f2bf(selu_f(v));
        } else {
          const int b = row >> 11;
          const float g = cm[b * 6144 + 5 * 1024 + col];
          of32[(size_t)row * N + col] = resid[(size_t)row * N + col] + g * v;
        }
      }
    }
  }
}

// ---------------- RoPE + repack: qkv -> Q[bh][t][d], K[bh][t][d], Vt[bh][d][t] ----------------
__global__ __launch_bounds__(256) void rope_pack(
    const unsigned short* __restrict__ qkv, const float* __restrict__ cosp,
    const float* __restrict__ sinp, const float* __restrict__ scalep,
    unsigned short* __restrict__ Qo, unsigned short* __restrict__ Ko,
    unsigned short* __restrict__ Vt) {
  const int tid = threadIdx.x;
  const int blk = blockIdx.x;
  const int tt = blk & 31, bh = blk >> 5;
  const int b = bh >> 4, h = bh & 15;
  const int t0 = tt * 64;
  __shared__ __align__(16) unsigned short tile[64][192];  // [t][q0..63|k64..127|v128..191]
#pragma unroll
  for (int i = 0; i < 6; ++i) {
    int cidx = i * 256 + tid;
    int r = cidx / 24, sg = cidx % 24;
    int colbase = (sg < 8) ? (h * 64 + sg * 8)
                : (sg < 16) ? (Cn + h * 64 + (sg - 8) * 8)
                            : (2 * Cn + h * 64 + (sg - 16) * 8);
    u16x8 v = *(const u16x8*)(qkv + (size_t)(b * Tn + t0 + r) * 3072 + colbase);
    *(u16x8*)(&tile[r][sg * 8]) = v;
  }
  __syncthreads();
  {
    const int t = tid >> 2, d0 = (tid & 3) * 16;
    const int tg = t0 + t;
    float co[16], si[16], sc[16];
#pragma unroll
    for (int i = 0; i < 4; ++i) {
      *(float4*)(co + i * 4) = *(const float4*)(cosp + (size_t)tg * 64 + d0 + i * 4);
      *(float4*)(si + i * 4) = *(const float4*)(sinp + (size_t)tg * 64 + d0 + i * 4);
      *(float4*)(sc + i * 4) = *(const float4*)(scalep + (size_t)tg * 64 + d0 + i * 4);
    }
    u16x8 qv[2], kv[2];
    unsigned short* qo = (unsigned short*)qv;
    unsigned short* ko = (unsigned short*)kv;
#pragma unroll
    for (int i = 0; i < 8; ++i) {
      int d = 2 * i;
      float q0 = bf2f(tile[t][d0 + d]), q1 = bf2f(tile[t][d0 + d + 1]);
      float k0 = bf2f(tile[t][64 + d0 + d]), k1 = bf2f(tile[t][64 + d0 + d + 1]);
      float qr0 = (q0 * co[d] - q1 * si[d]) * sc[d];
      float qr1 = (q1 * co[d + 1] + q0 * si[d + 1]) * sc[d + 1];
      float kr0 = (k0 * co[d] - k1 * si[d]) / sc[d];
      float kr1 = (k1 * co[d + 1] + k0 * si[d + 1]) / sc[d + 1];
      qo[d] = f2bf(qr0); qo[d + 1] = f2bf(qr1);
      ko[d] = f2bf(kr0); ko[d + 1] = f2bf(kr1);
    }
    size_t obase = ((size_t)bh * Tn + tg) * 64 + d0;
    *(u16x8*)(Qo + obase) = qv[0];
    *(u16x8*)(Qo + obase + 8) = qv[1];
    *(u16x8*)(Ko + obase) = kv[0];
    *(u16x8*)(Ko + obase + 8) = kv[1];
  }
  {
    const int d = tid >> 2, ts = (tid & 3) * 16;
    u16x8 vv[2];
    unsigned short* vp = (unsigned short*)vv;
#pragma unroll
    for (int j = 0; j < 16; ++j) vp[j] = tile[ts + j][128 + d];
    size_t obase = ((size_t)bh * 64 + d) * Tn + t0 + ts;
    *(u16x8*)(Vt + obase) = vv[0];
    *(u16x8*)(Vt + obase + 8) = vv[1];
  }
}

// ---------------- causal flash attention (swapped QK^T, in-register softmax) ----------------
// x2 = x + gate*attn. One wave = 16 queries; block = 4 waves = 64 q, processes 2
// paired q-tiles (i, 31-i) for uniform work. No block-level sync needed.
__global__ __launch_bounds__(256) void attn_kernel(
    const unsigned short* __restrict__ Q, const unsigned short* __restrict__ Kb,
    const unsigned short* __restrict__ Vt, const float* __restrict__ x,
    const float* __restrict__ cm, float* __restrict__ x2) {
  const int pair = blockIdx.x & 15;
  const int bh = blockIdx.x >> 4;
  const int b = bh >> 4, h = bh & 15;
  const int tid = threadIdx.x;
  const int w = tid >> 6, l = tid & 63;
  const int lr = l & 15, lg = l >> 4;
  const float inv_tp = 0.08838834764831845f;  // 1/sqrt(2*64)

  const unsigned short* Kbase = Kb + (size_t)bh * Tn * 64;
  const unsigned short* Vbase = Vt + (size_t)bh * 64 * Tn;

#ifndef HAVE_MFMA16
  __shared__ __align__(16) unsigned short P_lds[4][16][40];  // [wave][q][key(+pad)]
#endif

#pragma unroll
  for (int half = 0; half < 2; ++half) {
    const int qt = half ? (31 - pair) : pair;
    const int q0w = qt * 64 + w * 16;

    // Q fragments (B-operand of swapped QK^T): lane reads Q[q0w+lr][d-chunk]
    const unsigned short* Qp = Q + ((size_t)bh * Tn + q0w) * 64;
    s16x8 qa0 = *(const s16x8*)(Qp + lr * 64 + lg * 8);
    s16x8 qa1 = *(const s16x8*)(Qp + lr * 64 + 32 + lg * 8);

    f32x4 o[4];  // O^T: [d-tile][reg] ; lane holds d = dt*16+lg*4+r, q = q0w+lr
#pragma unroll
    for (int dt = 0; dt < 4; ++dt) o[dt] = (f32x4){0.f, 0.f, 0.f, 0.f};
    float mrow = -1e30f, lsum = 0.f;  // per-lane: stats for query q0w+lr

    const int ntiles = (q0w + 47) >> 5;
    for (int kt = 0; kt < ntiles; ++kt) {
      const int kb = kt * 32;
      // S^T = K·Q^T : row = key, col = query
      f32x4 st[2];
#pragma unroll
      for (int cc = 0; cc < 2; ++cc) {
        const unsigned short* Kp = Kbase + (size_t)(kb + cc * 16 + lr) * 64 + lg * 8;
        s16x8 ka = *(const s16x8*)(Kp);
        s16x8 kbb = *(const s16x8*)(Kp + 32);
        f32x4 t = (f32x4){0.f, 0.f, 0.f, 0.f};
        t = __builtin_amdgcn_mfma_f32_16x16x32_bf16(ka, qa0, t, 0, 0, 0);
        t = __builtin_amdgcn_mfma_f32_16x16x32_bf16(kbb, qa1, t, 0, 0, 0);
        st[cc] = t;
      }
      const int q = q0w + lr;
      float tmax = -1e30f;
#pragma unroll
      for (int cc = 0; cc < 2; ++cc)
#pragma unroll
        for (int r = 0; r < 4; ++r) {
          const int key = kb + cc * 16 + lg * 4 + r;
          float s = st[cc][r] * inv_tp;
          if (key > q) s = -1e30f;
          st[cc][r] = s;
          tmax = fmaxf(tmax, s);
        }
      tmax = fmaxf(tmax, __shfl_xor(tmax, 16, 64));
      tmax = fmaxf(tmax, __shfl_xor(tmax, 32, 64));
      const float mn = fmaxf(mrow, tmax);
      const float alpha = __expf(mrow - mn);
      mrow = mn;
      float p[2][4];
      float part = 0.f;
#pragma unroll
      for (int cc = 0; cc < 2; ++cc)
#pragma unroll
        for (int r = 0; r < 4; ++r) {
          p[cc][r] = __expf(st[cc][r] - mn);
          part += p[cc][r];
        }
      part += __shfl_xor(part, 16, 64);
      part += __shfl_xor(part, 32, 64);
      lsum = lsum * alpha + part;
#pragma unroll
      for (int dt = 0; dt < 4; ++dt)
#pragma unroll
        for (int r = 0; r < 4; ++r) o[dt][r] *= alpha;

#ifdef HAVE_MFMA16
      // P^T (C-layout) == B-fragment of 16x16x16 mfma: zero cross-lane traffic.
      s16x4 pb[2];
#pragma unroll
      for (int cc = 0; cc < 2; ++cc) {
        union { unsigned int u[2]; s16x4 v; } pk;
        pk.u[0] = cvt_pk_bf16(p[cc][0], p[cc][1]);
        pk.u[1] = cvt_pk_bf16(p[cc][2], p[cc][3]);
        pb[cc] = pk.v;
      }
#pragma unroll
      for (int dt = 0; dt < 4; ++dt) {
#pragma unroll
        for (int cc = 0; cc < 2; ++cc) {
          const s16x4 va = *(const s16x4*)(Vbase + (size_t)(dt * 16 + lr) * Tn + kb + cc * 16 + lg * 4);
          o[dt] = __builtin_amdgcn_mfma_f32_16x16x16bf16_1k(va, pb[cc], o[dt], 0, 0, 0);
        }
      }
#else
      // fallback: P via per-wave LDS, PV with 16x16x32
      {
        unsigned int u0a = cvt_pk_bf16(p[0][0], p[0][1]);
        unsigned int u0b = cvt_pk_bf16(p[0][2], p[0][3]);
        unsigned int u1a = cvt_pk_bf16(p[1][0], p[1][1]);
        unsigned int u1b = cvt_pk_bf16(p[1][2], p[1][3]);
        uint2 w0; w0.x = u0a; w0.y = u0b;
        uint2 w1; w1.x = u1a; w1.y = u1b;
        *(uint2*)(&P_lds[w][lr][lg * 4]) = w0;
        *(uint2*)(&P_lds[w][lr][16 + lg * 4]) = w1;
      }
      asm volatile("s_waitcnt lgkmcnt(0)" ::: "memory");
      __builtin_amdgcn_sched_barrier(0);
      {
        s16x8 pa = *(const s16x8*)(&P_lds[w][lr][lg * 8]);
#pragma unroll
        for (int dt = 0; dt < 4; ++dt) {
          const s16x8 va = *(const s16x8*)(Vbase + (size_t)(dt * 16 + lr) * Tn + kb + lg * 8);
          o[dt] = __builtin_amdgcn_mfma_f32_16x16x32_bf16(va, pa, o[dt], 0, 0, 0);
        }
      }
#endif
    }

    // epilogue: normalize, gate, residual. lane: q = q0w+lr, d = dt*16+lg*4+r
    const float rinv = 1.f / lsum;
    const int q = q0w + lr;
#pragma unroll
    for (int dt = 0; dt < 4; ++dt) {
      const int colb = h * 64 + dt * 16 + lg * 4;
      const size_t idx = ((size_t)b * Tn + q) * Cn + colb;
      float4 xv = *(const float4*)(x + idx);
      float4 gv = *(const float4*)(cm + b * 6144 + 2048 + colb);
      float4 ov;
      ov.x = xv.x + gv.x * o[dt][0] * rinv;
      ov.y = xv.y + gv.y * o[dt][1] * rinv;
      ov.z = xv.z + gv.z * o[dt][2] * rinv;
      ov.w = xv.w + gv.w * o[dt][3] * rinv;
      *(float4*)(x2 + idx) = ov;
    }
  }
}

// ---------------- launch ----------------
extern "C" void kernel_launch(void* const* d_in, const int* in_sizes, int n_in,
                              void* d_out, int out_size, void* d_ws, size_t ws_size,
                              hipStream_t stream) {
  (void)in_sizes; (void)n_in; (void)out_size; (void)ws_size;
  const float* x = (const float*)d_in[0];
  const float* pe_cos = (const float*)d_in[1];
  const float* pe_sin = (const float*)d_in[2];
  const float* pe_scale = (const float*)d_in[3];
  const float* cc = (const float*)d_in[4];
  // d_in[5] = mask: causal, computed analytically
  const float* qkv_w = (const float*)d_in[6];
  const float* qkv_b = (const float*)d_in[7];
  const float* w1 = (const float*)d_in[8];
  const float* b1 = (const float*)d_in[9];
  const float* w2 = (const float*)d_in[10];
  const float* b2 = (const float*)d_in[11];
  const float* ada_w = (const float*)d_in[12];
  const float* ada_b = (const float*)d_in[13];
  float* out = (float*)d_out;
  char* ws = (char*)d_ws;

  unsigned short* qkvw_bf = (unsigned short*)(ws + 0);
  unsigned short* w1_bf = (unsigned short*)(ws + 6291456);
  unsigned short* w2_bf = (unsigned short*)(ws + 14680064);
  float* cm = (float*)(ws + 23068672);
  unsigned short* h1 = (unsigned short*)(ws + 23117824);   // reused as h2
  unsigned short* qkvb = (unsigned short*)(ws + 31506432); // reused (+Q) as ff1
  unsigned short* Qb = (unsigned short*)(ws + 56672256);
  unsigned short* Kb2 = (unsigned short*)(ws + 65060864);
  unsigned short* Vtb = (unsigned short*)(ws + 73449472);
  float* x2b = (float*)(ws + 81838080);
  unsigned short* ff1b = (unsigned short*)(ws + 31506432);
  // total ws use: 98,615,296 bytes

  cast_f32_bf16<<<3072, 256, 0, stream>>>(qkv_w, qkvw_bf);
  cast_f32_bf16<<<4096, 256, 0, stream>>>(w1, w1_bf);
  cast_f32_bf16<<<4096, 256, 0, stream>>>(w2, w2_bf);
  modulation<<<3072, 256, 0, stream>>>(cc, ada_w, ada_b, cm);
  ln_mod<<<4096, 256, 0, stream>>>(x, cm, h1, 0, 1024);
  gemm_bt<0><<<dim3(24, 32), 256, 0, stream>>>(h1, qkvw_bf, qkv_b, qkvb, nullptr, nullptr, nullptr, 4096, 3072, 1024);
  rope_pack<<<1024, 256, 0, stream>>>(qkvb, pe_cos, pe_sin, pe_scale, Qb, Kb2, Vtb);
  attn_kernel<<<512, 256, 0, stream>>>(Qb, Kb2, Vtb, x, cm, x2b);
  ln_mod<<<4096, 256, 0, stream>>>(x2b, cm, h1, 3072, 4096);
  gemm_bt<1><<<dim3(32, 32), 256, 0, stream>>>(h1, w1_bf, b1, ff1b, nullptr, nullptr, nullptr, 4096, 4096, 1024);
  gemm_bt<2><<<dim3(8, 32), 256, 0, stream>>>(ff1b, w2_bf, b2, nullptr, out, x2b, cm, 4096, 1024, 4096);
}

// Round 3
// 372.485 us; speedup vs baseline: 1.2617x; 1.1202x over previous
//
#include <hip/hip_runtime.h>

#define Bn 2
#define Tn 2048
#define Cn 1024
#define NHn 16

typedef __attribute__((ext_vector_type(8))) short s16x8;
typedef __attribute__((ext_vector_type(4))) short s16x4;
typedef __attribute__((ext_vector_type(4))) float f32x4;
typedef __attribute__((ext_vector_type(8))) unsigned short u16x8;
typedef __attribute__((ext_vector_type(4))) unsigned short u16x4;
typedef const __attribute__((address_space(1))) void* gas_t;
typedef __attribute__((address_space(3))) void* las_t;

#if defined(__has_builtin)
#if __has_builtin(__builtin_amdgcn_mfma_f32_16x16x16bf16_1k)
#define HAVE_MFMA16 1
#endif
#endif

__device__ __forceinline__ void gl_lds16(const void* g, void* l) {
  __builtin_amdgcn_global_load_lds((gas_t)g, (las_t)l, 16, 0, 0);
}

__device__ __forceinline__ float bf2f(unsigned short u) {
  unsigned int x = ((unsigned int)u) << 16;
  float f; __builtin_memcpy(&f, &x, 4); return f;
}
__device__ __forceinline__ unsigned short f2bf(float f) {
  unsigned int x; __builtin_memcpy(&x, &f, 4);
  x += 0x7fffu + ((x >> 16) & 1u);
  return (unsigned short)(x >> 16);
}
__device__ __forceinline__ unsigned int cvt_pk_bf16(float a, float b) {
  unsigned int r;
  asm("v_cvt_pk_bf16_f32 %0, %1, %2" : "=v"(r) : "v"(a), "v"(b));
  return r;
}
__device__ __forceinline__ float selu_f(float x) {
  const float SC = 1.0507009873554805f, AL = 1.6732632423543772f;
  return x > 0.f ? SC * x : SC * AL * (__expf(x) - 1.f);
}
__device__ __forceinline__ float waveRS(float v) {
#pragma unroll
  for (int m = 32; m; m >>= 1) v += __shfl_xor(v, m, 64);
  return v;
}

// ---------------- cast f32 -> bf16 (weights) ----------------
__global__ __launch_bounds__(256) void cast_f32_bf16(
    const float* __restrict__ in, unsigned short* __restrict__ out) {
  size_t i = ((size_t)blockIdx.x * 256 + threadIdx.x) * 4;
  float4 v = *(const float4*)(in + i);
  u16x4 o;
  o.x = f2bf(v.x); o.y = f2bf(v.y); o.z = f2bf(v.z); o.w = f2bf(v.w);
  *(u16x4*)(out + i) = o;
}

// ---------------- modulation: cm = selu(c) @ ada_w.T + ada_b ----------------
__global__ __launch_bounds__(256) void modulation(
    const float* __restrict__ cin, const float* __restrict__ ada_w,
    const float* __restrict__ ada_b, float* __restrict__ cm) {
  const int tid = threadIdx.x;
  const int w = tid >> 6, l = tid & 63;
  const int rowg = blockIdx.x * 4 + w;          // 0..12287
  const int b = rowg / 6144, j = rowg % 6144;
  __shared__ float sc[1024];
#pragma unroll
  for (int i = 0; i < 4; ++i) {
    int idx = i * 256 + tid;
    sc[idx] = selu_f(cin[b * 1024 + idx]);
  }
  __syncthreads();
  const float* wr_ = ada_w + (size_t)j * 1024;
  float acc = 0.f;
#pragma unroll
  for (int i = 0; i < 4; ++i) {
    float4 wv = *(const float4*)(wr_ + (i * 64 + l) * 4);
    const float* sp = sc + (i * 64 + l) * 4;
    acc += wv.x * sp[0] + wv.y * sp[1] + wv.z * sp[2] + wv.w * sp[3];
  }
  acc = waveRS(acc);
  if (l == 0) cm[(size_t)b * 6144 + j] = acc + ada_b[j];
}

// ---------------- LN + AdaLN modulate -> bf16 ----------------
__global__ __launch_bounds__(256) void ln_mod(
    const float* __restrict__ xin, const float* __restrict__ cm,
    unsigned short* __restrict__ hout, int shift_off, int scale_off) {
  const int tid = threadIdx.x;
  const int row = blockIdx.x;
  const int b = row >> 11;
  const float* xr = xin + (size_t)row * 1024;
  float v[4]; float s = 0.f, s2 = 0.f;
#pragma unroll
  for (int i = 0; i < 4; ++i) {
    v[i] = xr[i * 256 + tid]; s += v[i]; s2 += v[i] * v[i];
  }
  __shared__ float rs[8];
  s = waveRS(s); s2 = waveRS(s2);
  const int w = tid >> 6, l = tid & 63;
  if (l == 0) { rs[w] = s; rs[4 + w] = s2; }
  __syncthreads();
  s = rs[0] + rs[1] + rs[2] + rs[3];
  s2 = rs[4] + rs[5] + rs[6] + rs[7];
  float mean = s * (1.f / 1024.f);
  float var = s2 * (1.f / 1024.f) - mean * mean;
  float rstd = rsqrtf(var + 1e-6f);
  const float* cb = cm + b * 6144;
#pragma unroll
  for (int i = 0; i < 4; ++i) {
    int ch = i * 256 + tid;
    float hv = (v[i] - mean) * rstd * (1.f + cb[scale_off + ch]) + cb[shift_off + ch];
    hout[(size_t)row * 1024 + ch] = f2bf(hv);
  }
}

// ---------------- GEMM: out[M][N] = A[M][K](bf16) * Bw[N][K](bf16)^T ----------------
// MODE 0: +bias -> bf16 ; MODE 1: selu(+bias) -> bf16 ; MODE 2: x2 + gate_f*(+bias) -> f32
template <int MODE>
__global__ __launch_bounds__(256) void gemm_bt(
    const unsigned short* __restrict__ A, const unsigned short* __restrict__ Bw,
    const float* __restrict__ bias, unsigned short* __restrict__ obf,
    float* __restrict__ of32, const float* __restrict__ resid,
    const float* __restrict__ cm, int M, int N, int K) {
  __shared__ unsigned short As[128 * 32];
  __shared__ unsigned short Bs[128 * 32];
  const int tid = threadIdx.x;
  const int bm = blockIdx.y, bn = blockIdx.x;
  const int w = tid >> 6, l = tid & 63;
  const int wr = w >> 1, wc = w & 1;
  const int lr = l & 15, lg = l >> 4;

  f32x4 acc[4][4];
#pragma unroll
  for (int m = 0; m < 4; ++m)
#pragma unroll
    for (int n = 0; n < 4; ++n) acc[m][n] = (f32x4){0.f, 0.f, 0.f, 0.f};

  const int c0 = tid, c1 = tid + 256;
  const size_t a0 = (size_t)(bm * 128 + (c0 >> 2)) * K + (c0 & 3) * 8;
  const size_t a1 = (size_t)(bm * 128 + (c1 >> 2)) * K + (c1 & 3) * 8;
  const size_t b0 = (size_t)(bn * 128 + (c0 >> 2)) * K + (c0 & 3) * 8;
  const size_t b1 = (size_t)(bn * 128 + (c1 >> 2)) * K + (c1 & 3) * 8;
  const int nkt = K >> 5;
  for (int kt = 0; kt < nkt; ++kt) {
    const int ko = kt * 32;
    __syncthreads();
    gl_lds16(A + a0 + ko, As + c0 * 8);
    gl_lds16(A + a1 + ko, As + c1 * 8);
    gl_lds16(Bw + b0 + ko, Bs + c0 * 8);
    gl_lds16(Bw + b1 + ko, Bs + c1 * 8);
    __syncthreads();
    s16x8 af[4], bf[4];
#pragma unroll
    for (int m = 0; m < 4; ++m)
      af[m] = *(const s16x8*)(As + (wr * 64 + m * 16 + lr) * 32 + lg * 8);
#pragma unroll
    for (int n = 0; n < 4; ++n)
      bf[n] = *(const s16x8*)(Bs + (wc * 64 + n * 16 + lr) * 32 + lg * 8);
#pragma unroll
    for (int m = 0; m < 4; ++m)
#pragma unroll
      for (int n = 0; n < 4; ++n)
        acc[m][n] = __builtin_amdgcn_mfma_f32_16x16x32_bf16(af[m], bf[n], acc[m][n], 0, 0, 0);
  }
#pragma unroll
  for (int m = 0; m < 4; ++m) {
#pragma unroll
    for (int n = 0; n < 4; ++n) {
      const int col = bn * 128 + wc * 64 + n * 16 + lr;
      const float bv = bias[col];
#pragma unroll
      for (int r = 0; r < 4; ++r) {
        const int row = bm * 128 + wr * 64 + m * 16 + lg * 4 + r;
        float v = acc[m][n][r] + bv;
        if (MODE == 0) {
          obf[(size_t)row * N + col] = f2bf(v);
        } else if (MODE == 1) {
          obf[(size_t)row * N + col] = f2bf(selu_f(v));
        } else {
          const int b = row >> 11;
          const float g = cm[b * 6144 + 5 * 1024 + col];
          of32[(size_t)row * N + col] = resid[(size_t)row * N + col] + g * v;
        }
      }
    }
  }
}

// ---------------- RoPE + repack: qkv -> Q[bh][t][d], K[bh][t][d], Vt[bh][d][t] ----------------
__global__ __launch_bounds__(256) void rope_pack(
    const unsigned short* __restrict__ qkv, const float* __restrict__ cosp,
    const float* __restrict__ sinp, const float* __restrict__ scalep,
    unsigned short* __restrict__ Qo, unsigned short* __restrict__ Ko,
    unsigned short* __restrict__ Vt) {
  const int tid = threadIdx.x;
  const int blk = blockIdx.x;
  const int tt = blk & 31, bh = blk >> 5;
  const int b = bh >> 4, h = bh & 15;
  const int t0 = tt * 64;
  __shared__ __align__(16) unsigned short tile[64][192];  // [t][q0..63|k64..127|v128..191]
#pragma unroll
  for (int i = 0; i < 6; ++i) {
    int cidx = i * 256 + tid;
    int r = cidx / 24, sg = cidx % 24;
    int colbase = (sg < 8) ? (h * 64 + sg * 8)
                : (sg < 16) ? (Cn + h * 64 + (sg - 8) * 8)
                            : (2 * Cn + h * 64 + (sg - 16) * 8);
    u16x8 v = *(const u16x8*)(qkv + (size_t)(b * Tn + t0 + r) * 3072 + colbase);
    *(u16x8*)(&tile[r][sg * 8]) = v;
  }
  __syncthreads();
  {
    const int t = tid >> 2, d0 = (tid & 3) * 16;
    const int tg = t0 + t;
    float co[16], si[16], sc[16];
#pragma unroll
    for (int i = 0; i < 4; ++i) {
      *(float4*)(co + i * 4) = *(const float4*)(cosp + (size_t)tg * 64 + d0 + i * 4);
      *(float4*)(si + i * 4) = *(const float4*)(sinp + (size_t)tg * 64 + d0 + i * 4);
      *(float4*)(sc + i * 4) = *(const float4*)(scalep + (size_t)tg * 64 + d0 + i * 4);
    }
    u16x8 qv[2], kv[2];
    unsigned short* qo = (unsigned short*)qv;
    unsigned short* ko = (unsigned short*)kv;
#pragma unroll
    for (int i = 0; i < 8; ++i) {
      int d = 2 * i;
      float q0 = bf2f(tile[t][d0 + d]), q1 = bf2f(tile[t][d0 + d + 1]);
      float k0 = bf2f(tile[t][64 + d0 + d]), k1 = bf2f(tile[t][64 + d0 + d + 1]);
      float qr0 = (q0 * co[d] - q1 * si[d]) * sc[d];
      float qr1 = (q1 * co[d + 1] + q0 * si[d + 1]) * sc[d + 1];
      float kr0 = (k0 * co[d] - k1 * si[d]) / sc[d];
      float kr1 = (k1 * co[d + 1] + k0 * si[d + 1]) / sc[d + 1];
      qo[d] = f2bf(qr0); qo[d + 1] = f2bf(qr1);
      ko[d] = f2bf(kr0); ko[d + 1] = f2bf(kr1);
    }
    size_t obase = ((size_t)bh * Tn + tg) * 64 + d0;
    *(u16x8*)(Qo + obase) = qv[0];
    *(u16x8*)(Qo + obase + 8) = qv[1];
    *(u16x8*)(Ko + obase) = kv[0];
    *(u16x8*)(Ko + obase + 8) = kv[1];
  }
  {
    const int d = tid >> 2, ts = (tid & 3) * 16;
    u16x8 vv[2];
    unsigned short* vp = (unsigned short*)vv;
#pragma unroll
    for (int j = 0; j < 16; ++j) vp[j] = tile[ts + j][128 + d];
    size_t obase = ((size_t)bh * 64 + d) * Tn + t0 + ts;
    *(u16x8*)(Vt + obase) = vv[0];
    *(u16x8*)(Vt + obase + 8) = vv[1];
  }
}

// ---------------- causal flash attention (swapped QK^T, in-register softmax) ----------------
// Wave = 32 queries (2 q-tiles). Block = 4 waves = 128 contiguous queries.
// XCD-locality: blk&7 selects XCD; each XCD owns 4 heads so K/V live in one L2.
// LPT: heaviest q-chunks dispatched first. x2 = x + gate*attn fused.
__global__ __launch_bounds__(256) void attn_kernel(
    const unsigned short* __restrict__ Q, const unsigned short* __restrict__ Kb,
    const unsigned short* __restrict__ Vt, const float* __restrict__ x,
    const float* __restrict__ cm, float* __restrict__ x2) {
  const int blk = blockIdx.x;
  const int xcd = blk & 7, idx = blk >> 3;
  const int bh = xcd + 8 * (idx & 3);     // 4 heads per XCD
  const int qchunk = 15 - (idx >> 2);     // heavy chunks first (LPT)
  const int b = bh >> 4, h = bh & 15;
  const int tid = threadIdx.x;
  const int w = tid >> 6, l = tid & 63;
  const int lr = l & 15, lg = l >> 4;
  const int q0w = qchunk * 128 + w * 32;  // wave's 32 queries
  const float inv_tp = 0.08838834764831845f;  // 1/sqrt(2*64)

  const unsigned short* Kbase = Kb + (size_t)bh * Tn * 64;
  const unsigned short* Vbase = Vt + (size_t)bh * 64 * Tn;

#ifndef HAVE_MFMA16
  __shared__ __align__(16) unsigned short P_lds[4][2][16][40];
#endif

  // Q fragments (B-operand of swapped QK^T): lane reads Q[q][d-chunk]
  const unsigned short* Qp = Q + ((size_t)bh * Tn + q0w) * 64;
  s16x8 qa[2][2];
#pragma unroll
  for (int qt = 0; qt < 2; ++qt) {
    qa[qt][0] = *(const s16x8*)(Qp + (qt * 16 + lr) * 64 + lg * 8);
    qa[qt][1] = *(const s16x8*)(Qp + (qt * 16 + lr) * 64 + 32 + lg * 8);
  }

  f32x4 o[2][4];  // O^T per q-tile: lane holds d = dt*16+lg*4+r, q = q0w+qt*16+lr
#pragma unroll
  for (int qt = 0; qt < 2; ++qt)
#pragma unroll
    for (int dt = 0; dt < 4; ++dt) o[qt][dt] = (f32x4){0.f, 0.f, 0.f, 0.f};
  float mrow[2] = {-1e30f, -1e30f}, lsum[2] = {0.f, 0.f};

  const int ntiles = (q0w >> 5) + 1;
  for (int kt = 0; kt < ntiles; ++kt) {
    const int kb = kt * 32;
    // K fragments (shared across both q-tiles)
    s16x8 kf[2][2];
#pragma unroll
    for (int cc = 0; cc < 2; ++cc) {
      const unsigned short* Kp = Kbase + (size_t)(kb + cc * 16 + lr) * 64 + lg * 8;
      kf[cc][0] = *(const s16x8*)(Kp);
      kf[cc][1] = *(const s16x8*)(Kp + 32);
    }
#ifdef HAVE_MFMA16
    // V fragments — independent of P, issue early for ILP
    s16x4 vf[4][2];
#pragma unroll
    for (int dt = 0; dt < 4; ++dt)
#pragma unroll
      for (int cc = 0; cc < 2; ++cc)
        vf[dt][cc] = *(const s16x4*)(Vbase + (size_t)(dt * 16 + lr) * Tn + kb + cc * 16 + lg * 4);
#endif
    // S^T = K·Q^T : row = key, col = query
    f32x4 st[2][2];
#pragma unroll
    for (int qt = 0; qt < 2; ++qt)
#pragma unroll
      for (int cc = 0; cc < 2; ++cc) {
        f32x4 t = (f32x4){0.f, 0.f, 0.f, 0.f};
        t = __builtin_amdgcn_mfma_f32_16x16x32_bf16(kf[cc][0], qa[qt][0], t, 0, 0, 0);
        t = __builtin_amdgcn_mfma_f32_16x16x32_bf16(kf[cc][1], qa[qt][1], t, 0, 0, 0);
        st[qt][cc] = t;
      }
#pragma unroll
    for (int qt = 0; qt < 2; ++qt) {
      const int q = q0w + qt * 16 + lr;
      float tmax = -1e30f;
#pragma unroll
      for (int cc = 0; cc < 2; ++cc)
#pragma unroll
        for (int r = 0; r < 4; ++r) {
          const int key = kb + cc * 16 + lg * 4 + r;
          float s = st[qt][cc][r] * inv_tp;
          if (key > q) s = -1e30f;
          st[qt][cc][r] = s;
          tmax = fmaxf(tmax, s);
        }
      tmax = fmaxf(tmax, __shfl_xor(tmax, 16, 64));
      tmax = fmaxf(tmax, __shfl_xor(tmax, 32, 64));
      const float mn = fmaxf(mrow[qt], tmax);
      const float alpha = __expf(mrow[qt] - mn);
      mrow[qt] = mn;
      float p[2][4];
      float part = 0.f;
#pragma unroll
      for (int cc = 0; cc < 2; ++cc)
#pragma unroll
        for (int r = 0; r < 4; ++r) {
          p[cc][r] = __expf(st[qt][cc][r] - mn);
          part += p[cc][r];
        }
      part += __shfl_xor(part, 16, 64);
      part += __shfl_xor(part, 32, 64);
      lsum[qt] = lsum[qt] * alpha + part;
#pragma unroll
      for (int dt = 0; dt < 4; ++dt)
#pragma unroll
        for (int r = 0; r < 4; ++r) o[qt][dt][r] *= alpha;

#ifdef HAVE_MFMA16
      // P^T (C-layout) == B-fragment of 16x16x16 mfma: zero cross-lane traffic.
      s16x4 pb[2];
#pragma unroll
      for (int cc = 0; cc < 2; ++cc) {
        union { unsigned int u[2]; s16x4 v; } pk;
        pk.u[0] = cvt_pk_bf16(p[cc][0], p[cc][1]);
        pk.u[1] = cvt_pk_bf16(p[cc][2], p[cc][3]);
        pb[cc] = pk.v;
      }
#pragma unroll
      for (int dt = 0; dt < 4; ++dt)
#pragma unroll
        for (int cc = 0; cc < 2; ++cc)
          o[qt][dt] = __builtin_amdgcn_mfma_f32_16x16x16bf16_1k(vf[dt][cc], pb[cc], o[qt][dt], 0, 0, 0);
#else
      {
        unsigned int u0a = cvt_pk_bf16(p[0][0], p[0][1]);
        unsigned int u0b = cvt_pk_bf16(p[0][2], p[0][3]);
        unsigned int u1a = cvt_pk_bf16(p[1][0], p[1][1]);
        unsigned int u1b = cvt_pk_bf16(p[1][2], p[1][3]);
        uint2 w0; w0.x = u0a; w0.y = u0b;
        uint2 w1; w1.x = u1a; w1.y = u1b;
        *(uint2*)(&P_lds[w][qt][lr][lg * 4]) = w0;
        *(uint2*)(&P_lds[w][qt][lr][16 + lg * 4]) = w1;
      }
      asm volatile("s_waitcnt lgkmcnt(0)" ::: "memory");
      __builtin_amdgcn_sched_barrier(0);
      {
        s16x8 pa = *(const s16x8*)(&P_lds[w][qt][lr][lg * 8]);
#pragma unroll
        for (int dt = 0; dt < 4; ++dt) {
          const s16x8 va = *(const s16x8*)(Vbase + (size_t)(dt * 16 + lr) * Tn + kb + lg * 8);
          o[qt][dt] = __builtin_amdgcn_mfma_f32_16x16x32_bf16(va, pa, o[qt][dt], 0, 0, 0);
        }
      }
#endif
    }
  }

  // epilogue: normalize, gate, residual. lane: q = q0w+qt*16+lr, d = dt*16+lg*4+r
#pragma unroll
  for (int qt = 0; qt < 2; ++qt) {
    const float rinv = 1.f / lsum[qt];
    const int q = q0w + qt * 16 + lr;
#pragma unroll
    for (int dt = 0; dt < 4; ++dt) {
      const int colb = h * 64 + dt * 16 + lg * 4;
      const size_t idx2 = ((size_t)b * Tn + q) * Cn + colb;
      float4 xv = *(const float4*)(x + idx2);
      float4 gv = *(const float4*)(cm + b * 6144 + 2048 + colb);
      float4 ov;
      ov.x = xv.x + gv.x * o[qt][dt][0] * rinv;
      ov.y = xv.y + gv.y * o[qt][dt][1] * rinv;
      ov.z = xv.z + gv.z * o[qt][dt][2] * rinv;
      ov.w = xv.w + gv.w * o[qt][dt][3] * rinv;
      *(float4*)(x2 + idx2) = ov;
    }
  }
}

// ---------------- launch ----------------
extern "C" void kernel_launch(void* const* d_in, const int* in_sizes, int n_in,
                              void* d_out, int out_size, void* d_ws, size_t ws_size,
                              hipStream_t stream) {
  (void)in_sizes; (void)n_in; (void)out_size; (void)ws_size;
  const float* x = (const float*)d_in[0];
  const float* pe_cos = (const float*)d_in[1];
  const float* pe_sin = (const float*)d_in[2];
  const float* pe_scale = (const float*)d_in[3];
  const float* cc = (const float*)d_in[4];
  // d_in[5] = mask: causal, computed analytically
  const float* qkv_w = (const float*)d_in[6];
  const float* qkv_b = (const float*)d_in[7];
  const float* w1 = (const float*)d_in[8];
  const float* b1 = (const float*)d_in[9];
  const float* w2 = (const float*)d_in[10];
  const float* b2 = (const float*)d_in[11];
  const float* ada_w = (const float*)d_in[12];
  const float* ada_b = (const float*)d_in[13];
  float* out = (float*)d_out;
  char* ws = (char*)d_ws;

  unsigned short* qkvw_bf = (unsigned short*)(ws + 0);
  unsigned short* w1_bf = (unsigned short*)(ws + 6291456);
  unsigned short* w2_bf = (unsigned short*)(ws + 14680064);
  float* cm = (float*)(ws + 23068672);
  unsigned short* h1 = (unsigned short*)(ws + 23117824);   // reused as h2
  unsigned short* qkvb = (unsigned short*)(ws + 31506432); // reused (+Q) as ff1
  unsigned short* Qb = (unsigned short*)(ws + 56672256);
  unsigned short* Kb2 = (unsigned short*)(ws + 65060864);
  unsigned short* Vtb = (unsigned short*)(ws + 73449472);
  float* x2b = (float*)(ws + 81838080);
  unsigned short* ff1b = (unsigned short*)(ws + 31506432);
  // total ws use: 98,615,296 bytes

  cast_f32_bf16<<<3072, 256, 0, stream>>>(qkv_w, qkvw_bf);
  cast_f32_bf16<<<4096, 256, 0, stream>>>(w1, w1_bf);
  cast_f32_bf16<<<4096, 256, 0, stream>>>(w2, w2_bf);
  modulation<<<3072, 256, 0, stream>>>(cc, ada_w, ada_b, cm);
  ln_mod<<<4096, 256, 0, stream>>>(x, cm, h1, 0, 1024);
  gemm_bt<0><<<dim3(24, 32), 256, 0, stream>>>(h1, qkvw_bf, qkv_b, qkvb, nullptr, nullptr, nullptr, 4096, 3072, 1024);
  rope_pack<<<1024, 256, 0, stream>>>(qkvb, pe_cos, pe_sin, pe_scale, Qb, Kb2, Vtb);
  attn_kernel<<<512, 256, 0, stream>>>(Qb, Kb2, Vtb, x, cm, x2b);
  ln_mod<<<4096, 256, 0, stream>>>(x2b, cm, h1, 3072, 4096);
  gemm_bt<1><<<dim3(32, 32), 256, 0, stream>>>(h1, w1_bf, b1, ff1b, nullptr, nullptr, nullptr, 4096, 4096, 1024);
  gemm_bt<2><<<dim3(8, 32), 256, 0, stream>>>(ff1b, w2_bf, b2, nullptr, out, x2b, cm, 4096, 1024, 4096);
}

// Round 5
// 371.144 us; speedup vs baseline: 1.2663x; 1.0036x over previous
//
#include <hip/hip_runtime.h>

#define Bn 2
#define Tn 2048
#define Cn 1024
#define NHn 16

typedef __attribute__((ext_vector_type(8))) short s16x8;
typedef __attribute__((ext_vector_type(4))) short s16x4;
typedef __attribute__((ext_vector_type(4))) float f32x4;
typedef __attribute__((ext_vector_type(8))) unsigned short u16x8;
typedef __attribute__((ext_vector_type(4))) unsigned short u16x4;
typedef const __attribute__((address_space(1))) void* gas_t;
typedef __attribute__((address_space(3))) void* las_t;

__device__ __forceinline__ void gl_lds16(const void* g, void* l) {
  __builtin_amdgcn_global_load_lds((gas_t)g, (las_t)l, 16, 0, 0);
}

__device__ __forceinline__ float bf2f(unsigned short u) {
  unsigned int x = ((unsigned int)u) << 16;
  float f; __builtin_memcpy(&f, &x, 4); return f;
}
__device__ __forceinline__ unsigned short f2bf(float f) {
  unsigned int x; __builtin_memcpy(&x, &f, 4);
  x += 0x7fffu + ((x >> 16) & 1u);
  return (unsigned short)(x >> 16);
}
__device__ __forceinline__ unsigned int cvt_pk_bf16(float a, float b) {
  unsigned int r;
  asm("v_cvt_pk_bf16_f32 %0, %1, %2" : "=v"(r) : "v"(a), "v"(b));
  return r;
}
// 16x16x16 bf16 MFMA; __has_builtin check inside the body so the HOST pass
// (where the amdgcn builtin doesn't exist) still parses.
__device__ __forceinline__ f32x4 mfma16_bf16(s16x4 a, s16x4 b, f32x4 c) {
#if defined(__has_builtin)
#if __has_builtin(__builtin_amdgcn_mfma_f32_16x16x16bf16_1k)
  return __builtin_amdgcn_mfma_f32_16x16x16bf16_1k(a, b, c, 0, 0, 0);
#else
  return c;  // host-pass parse only; device pass verified to have the builtin (r3: LDS=0)
#endif
#else
  return c;
#endif
}
__device__ __forceinline__ float selu_f(float x) {
  const float SC = 1.0507009873554805f, AL = 1.6732632423543772f;
  return x > 0.f ? SC * x : SC * AL * (__expf(x) - 1.f);
}
__device__ __forceinline__ float waveRS(float v) {
#pragma unroll
  for (int m = 32; m; m >>= 1) v += __shfl_xor(v, m, 64);
  return v;
}

// ---------------- cast f32 -> bf16 (weights) ----------------
__global__ __launch_bounds__(256) void cast_f32_bf16(
    const float* __restrict__ in, unsigned short* __restrict__ out) {
  size_t i = ((size_t)blockIdx.x * 256 + threadIdx.x) * 4;
  float4 v = *(const float4*)(in + i);
  u16x4 o;
  o.x = f2bf(v.x); o.y = f2bf(v.y); o.z = f2bf(v.z); o.w = f2bf(v.w);
  *(u16x4*)(out + i) = o;
}

// ---------------- modulation: cm = selu(c) @ ada_w.T + ada_b ----------------
__global__ __launch_bounds__(256) void modulation(
    const float* __restrict__ cin, const float* __restrict__ ada_w,
    const float* __restrict__ ada_b, float* __restrict__ cm) {
  const int tid = threadIdx.x;
  const int w = tid >> 6, l = tid & 63;
  const int rowg = blockIdx.x * 4 + w;          // 0..12287
  const int b = rowg / 6144, j = rowg % 6144;
  __shared__ float sc[1024];
#pragma unroll
  for (int i = 0; i < 4; ++i) {
    int idx = i * 256 + tid;
    sc[idx] = selu_f(cin[b * 1024 + idx]);
  }
  __syncthreads();
  const float* wr_ = ada_w + (size_t)j * 1024;
  float acc = 0.f;
#pragma unroll
  for (int i = 0; i < 4; ++i) {
    float4 wv = *(const float4*)(wr_ + (i * 64 + l) * 4);
    const float* sp = sc + (i * 64 + l) * 4;
    acc += wv.x * sp[0] + wv.y * sp[1] + wv.z * sp[2] + wv.w * sp[3];
  }
  acc = waveRS(acc);
  if (l == 0) cm[(size_t)b * 6144 + j] = acc + ada_b[j];
}

// ---------------- LN + AdaLN modulate -> bf16 ----------------
__global__ __launch_bounds__(256) void ln_mod(
    const float* __restrict__ xin, const float* __restrict__ cm,
    unsigned short* __restrict__ hout, int shift_off, int scale_off) {
  const int tid = threadIdx.x;
  const int row = blockIdx.x;
  const int b = row >> 11;
  const float* xr = xin + (size_t)row * 1024;
  float v[4]; float s = 0.f, s2 = 0.f;
#pragma unroll
  for (int i = 0; i < 4; ++i) {
    v[i] = xr[i * 256 + tid]; s += v[i]; s2 += v[i] * v[i];
  }
  __shared__ float rs[8];
  s = waveRS(s); s2 = waveRS(s2);
  const int w = tid >> 6, l = tid & 63;
  if (l == 0) { rs[w] = s; rs[4 + w] = s2; }
  __syncthreads();
  s = rs[0] + rs[1] + rs[2] + rs[3];
  s2 = rs[4] + rs[5] + rs[6] + rs[7];
  float mean = s * (1.f / 1024.f);
  float var = s2 * (1.f / 1024.f) - mean * mean;
  float rstd = rsqrtf(var + 1e-6f);
  const float* cb = cm + b * 6144;
#pragma unroll
  for (int i = 0; i < 4; ++i) {
    int ch = i * 256 + tid;
    float hv = (v[i] - mean) * rstd * (1.f + cb[scale_off + ch]) + cb[shift_off + ch];
    hout[(size_t)row * 1024 + ch] = f2bf(hv);
  }
}

// ---------------- GEMM: out[M][N] = A[M][K](bf16) * Bw[N][K](bf16)^T ----------------
// MODE 0: +bias -> bf16 ; MODE 1: selu(+bias) -> bf16 ; MODE 2: x2 + gate_f*(+bias) -> f32
template <int MODE>
__global__ __launch_bounds__(256) void gemm_bt(
    const unsigned short* __restrict__ A, const unsigned short* __restrict__ Bw,
    const float* __restrict__ bias, unsigned short* __restrict__ obf,
    float* __restrict__ of32, const float* __restrict__ resid,
    const float* __restrict__ cm, int M, int N, int K) {
  __shared__ unsigned short As[128 * 32];
  __shared__ unsigned short Bs[128 * 32];
  const int tid = threadIdx.x;
  const int bm = blockIdx.y, bn = blockIdx.x;
  const int w = tid >> 6, l = tid & 63;
  const int wr = w >> 1, wc = w & 1;
  const int lr = l & 15, lg = l >> 4;

  f32x4 acc[4][4];
#pragma unroll
  for (int m = 0; m < 4; ++m)
#pragma unroll
    for (int n = 0; n < 4; ++n) acc[m][n] = (f32x4){0.f, 0.f, 0.f, 0.f};

  const int c0 = tid, c1 = tid + 256;
  const size_t a0 = (size_t)(bm * 128 + (c0 >> 2)) * K + (c0 & 3) * 8;
  const size_t a1 = (size_t)(bm * 128 + (c1 >> 2)) * K + (c1 & 3) * 8;
  const size_t b0 = (size_t)(bn * 128 + (c0 >> 2)) * K + (c0 & 3) * 8;
  const size_t b1 = (size_t)(bn * 128 + (c1 >> 2)) * K + (c1 & 3) * 8;
  const int nkt = K >> 5;
  for (int kt = 0; kt < nkt; ++kt) {
    const int ko = kt * 32;
    __syncthreads();
    gl_lds16(A + a0 + ko, As + c0 * 8);
    gl_lds16(A + a1 + ko, As + c1 * 8);
    gl_lds16(Bw + b0 + ko, Bs + c0 * 8);
    gl_lds16(Bw + b1 + ko, Bs + c1 * 8);
    __syncthreads();
    s16x8 af[4], bf[4];
#pragma unroll
    for (int m = 0; m < 4; ++m)
      af[m] = *(const s16x8*)(As + (wr * 64 + m * 16 + lr) * 32 + lg * 8);
#pragma unroll
    for (int n = 0; n < 4; ++n)
      bf[n] = *(const s16x8*)(Bs + (wc * 64 + n * 16 + lr) * 32 + lg * 8);
#pragma unroll
    for (int m = 0; m < 4; ++m)
#pragma unroll
      for (int n = 0; n < 4; ++n)
        acc[m][n] = __builtin_amdgcn_mfma_f32_16x16x32_bf16(af[m], bf[n], acc[m][n], 0, 0, 0);
  }
#pragma unroll
  for (int m = 0; m < 4; ++m) {
#pragma unroll
    for (int n = 0; n < 4; ++n) {
      const int col = bn * 128 + wc * 64 + n * 16 + lr;
      const float bv = bias[col];
#pragma unroll
      for (int r = 0; r < 4; ++r) {
        const int row = bm * 128 + wr * 64 + m * 16 + lg * 4 + r;
        float v = acc[m][n][r] + bv;
        if (MODE == 0) {
          obf[(size_t)row * N + col] = f2bf(v);
        } else if (MODE == 1) {
          obf[(size_t)row * N + col] = f2bf(selu_f(v));
        } else {
          const int b = row >> 11;
          const float g = cm[b * 6144 + 5 * 1024 + col];
          of32[(size_t)row * N + col] = resid[(size_t)row * N + col] + g * v;
        }
      }
    }
  }
}

// ---------------- RoPE + repack: qkv -> Q[bh][t][d], K[bh][t][d], Vt[bh][d][t] ----------------
__global__ __launch_bounds__(256) void rope_pack(
    const unsigned short* __restrict__ qkv, const float* __restrict__ cosp,
    const float* __restrict__ sinp, const float* __restrict__ scalep,
    unsigned short* __restrict__ Qo, unsigned short* __restrict__ Ko,
    unsigned short* __restrict__ Vt) {
  const int tid = threadIdx.x;
  const int blk = blockIdx.x;
  const int tt = blk & 31, bh = blk >> 5;
  const int b = bh >> 4, h = bh & 15;
  const int t0 = tt * 64;
  __shared__ __align__(16) unsigned short tile[64][192];  // [t][q0..63|k64..127|v128..191]
#pragma unroll
  for (int i = 0; i < 6; ++i) {
    int cidx = i * 256 + tid;
    int r = cidx / 24, sg = cidx % 24;
    int colbase = (sg < 8) ? (h * 64 + sg * 8)
                : (sg < 16) ? (Cn + h * 64 + (sg - 8) * 8)
                            : (2 * Cn + h * 64 + (sg - 16) * 8);
    u16x8 v = *(const u16x8*)(qkv + (size_t)(b * Tn + t0 + r) * 3072 + colbase);
    *(u16x8*)(&tile[r][sg * 8]) = v;
  }
  __syncthreads();
  {
    const int t = tid >> 2, d0 = (tid & 3) * 16;
    const int tg = t0 + t;
    float co[16], si[16], sc[16];
#pragma unroll
    for (int i = 0; i < 4; ++i) {
      *(float4*)(co + i * 4) = *(const float4*)(cosp + (size_t)tg * 64 + d0 + i * 4);
      *(float4*)(si + i * 4) = *(const float4*)(sinp + (size_t)tg * 64 + d0 + i * 4);
      *(float4*)(sc + i * 4) = *(const float4*)(scalep + (size_t)tg * 64 + d0 + i * 4);
    }
    u16x8 qv[2], kv[2];
    unsigned short* qo = (unsigned short*)qv;
    unsigned short* ko = (unsigned short*)kv;
#pragma unroll
    for (int i = 0; i < 8; ++i) {
      int d = 2 * i;
      float q0 = bf2f(tile[t][d0 + d]), q1 = bf2f(tile[t][d0 + d + 1]);
      float k0 = bf2f(tile[t][64 + d0 + d]), k1 = bf2f(tile[t][64 + d0 + d + 1]);
      float qr0 = (q0 * co[d] - q1 * si[d]) * sc[d];
      float qr1 = (q1 * co[d + 1] + q0 * si[d + 1]) * sc[d + 1];
      float kr0 = (k0 * co[d] - k1 * si[d]) / sc[d];
      float kr1 = (k1 * co[d + 1] + k0 * si[d + 1]) / sc[d + 1];
      qo[d] = f2bf(qr0); qo[d + 1] = f2bf(qr1);
      ko[d] = f2bf(kr0); ko[d + 1] = f2bf(kr1);
    }
    size_t obase = ((size_t)bh * Tn + tg) * 64 + d0;
    *(u16x8*)(Qo + obase) = qv[0];
    *(u16x8*)(Qo + obase + 8) = qv[1];
    *(u16x8*)(Ko + obase) = kv[0];
    *(u16x8*)(Ko + obase + 8) = kv[1];
  }
  {
    const int d = tid >> 2, ts = (tid & 3) * 16;
    u16x8 vv[2];
    unsigned short* vp = (unsigned short*)vv;
#pragma unroll
    for (int j = 0; j < 16; ++j) vp[j] = tile[ts + j][128 + d];
    size_t obase = ((size_t)bh * 64 + d) * Tn + t0 + ts;
    *(u16x8*)(Vt + obase) = vv[0];
    *(u16x8*)(Vt + obase + 8) = vv[1];
  }
}

// ---------------- causal flash attention ----------------
// Swapped QK^T, in-register softmax, depth-1 SW pipeline (reg double-buffer),
// defer-max rescale (THR=8), diagonal-only masking. Wave = 32 queries.
// XCD-locality: blk&7 = XCD, 4 heads per XCD. LPT: heavy chunks first.
#define ATTN_LOAD(KB, KF, VF)                                                          \
  do {                                                                                 \
    const int kb_ = (KB);                                                              \
    _Pragma("unroll")                                                                  \
    for (int cc = 0; cc < 2; ++cc) {                                                   \
      const unsigned short* Kp = Kbase + (size_t)(kb_ + cc * 16 + lr) * 64 + lg * 8;   \
      KF[cc][0] = *(const s16x8*)(Kp);                                                 \
      KF[cc][1] = *(const s16x8*)(Kp + 32);                                            \
    }                                                                                  \
    _Pragma("unroll")                                                                  \
    for (int dt = 0; dt < 4; ++dt)                                                     \
      _Pragma("unroll")                                                                \
      for (int cc = 0; cc < 2; ++cc)                                                   \
        VF[dt][cc] = *(const s16x4*)(Vbase + (size_t)(dt * 16 + lr) * Tn + kb_ +       \
                                     cc * 16 + lg * 4);                                \
  } while (0)

#define ATTN_COMP(KB, KF, VF, DOMASK)                                                  \
  do {                                                                                 \
    const int kb_ = (KB);                                                              \
    const bool dm_ = (DOMASK);                                                         \
    f32x4 st[2][2];                                                                    \
    _Pragma("unroll")                                                                  \
    for (int qt = 0; qt < 2; ++qt)                                                     \
      _Pragma("unroll")                                                                \
      for (int cc = 0; cc < 2; ++cc) {                                                 \
        f32x4 t = (f32x4){0.f, 0.f, 0.f, 0.f};                                         \
        t = __builtin_amdgcn_mfma_f32_16x16x32_bf16(KF[cc][0], qa[qt][0], t, 0, 0, 0); \
        t = __builtin_amdgcn_mfma_f32_16x16x32_bf16(KF[cc][1], qa[qt][1], t, 0, 0, 0); \
        st[qt][cc] = t;                                                                \
      }                                                                                \
    _Pragma("unroll")                                                                  \
    for (int qt = 0; qt < 2; ++qt) {                                                   \
      const int q = q0w + qt * 16 + lr;                                                \
      float tmax = -1e30f;                                                             \
      _Pragma("unroll")                                                                \
      for (int cc = 0; cc < 2; ++cc)                                                   \
        _Pragma("unroll")                                                              \
        for (int r = 0; r < 4; ++r) {                                                  \
          float s = st[qt][cc][r] * inv_tp;                                            \
          if (dm_) {                                                                   \
            const int key = kb_ + cc * 16 + lg * 4 + r;                                \
            if (key > q) s = -1e30f;                                                   \
          }                                                                            \
          st[qt][cc][r] = s;                                                           \
          tmax = fmaxf(tmax, s);                                                       \
        }                                                                              \
      tmax = fmaxf(tmax, __shfl_xor(tmax, 16, 64));                                    \
      tmax = fmaxf(tmax, __shfl_xor(tmax, 32, 64));                                    \
      if (__any(tmax > mrow[qt] + 8.f)) {                                              \
        const float mn = fmaxf(mrow[qt], tmax);                                        \
        const float alpha = __expf(mrow[qt] - mn);                                     \
        mrow[qt] = mn;                                                                 \
        lsum[qt] *= alpha;                                                             \
        _Pragma("unroll")                                                              \
        for (int dt = 0; dt < 4; ++dt)                                                 \
          _Pragma("unroll")                                                            \
          for (int r = 0; r < 4; ++r) o[qt][dt][r] *= alpha;                           \
      }                                                                                \
      float p[2][4];                                                                   \
      float part = 0.f;                                                                \
      _Pragma("unroll")                                                                \
      for (int cc = 0; cc < 2; ++cc)                                                   \
        _Pragma("unroll")                                                              \
        for (int r = 0; r < 4; ++r) {                                                  \
          p[cc][r] = __expf(st[qt][cc][r] - mrow[qt]);                                 \
          part += p[cc][r];                                                            \
        }                                                                              \
      part += __shfl_xor(part, 16, 64);                                                \
      part += __shfl_xor(part, 32, 64);                                                \
      lsum[qt] += part;                                                                \
      s16x4 pb[2];                                                                     \
      _Pragma("unroll")                                                                \
      for (int cc = 0; cc < 2; ++cc) {                                                 \
        union { unsigned int u[2]; s16x4 v; } pk;                                      \
        pk.u[0] = cvt_pk_bf16(p[cc][0], p[cc][1]);                                     \
        pk.u[1] = cvt_pk_bf16(p[cc][2], p[cc][3]);                                     \
        pb[cc] = pk.v;                                                                 \
      }                                                                                \
      _Pragma("unroll")                                                                \
      for (int dt = 0; dt < 4; ++dt)                                                   \
        _Pragma("unroll")                                                              \
        for (int cc = 0; cc < 2; ++cc)                                                 \
          o[qt][dt] = mfma16_bf16(VF[dt][cc], pb[cc], o[qt][dt]);                      \
    }                                                                                  \
  } while (0)

__global__ __launch_bounds__(256) void attn_kernel(
    const unsigned short* __restrict__ Q, const unsigned short* __restrict__ Kb,
    const unsigned short* __restrict__ Vt, const float* __restrict__ x,
    const float* __restrict__ cm, float* __restrict__ x2) {
  const int blk = blockIdx.x;
  const int xcd = blk & 7, idx = blk >> 3;
  const int bh = xcd + 8 * (idx & 3);     // 4 heads per XCD
  const int qchunk = 15 - (idx >> 2);     // heavy chunks first (LPT)
  const int b = bh >> 4, h = bh & 15;
  const int tid = threadIdx.x;
  const int w = tid >> 6, l = tid & 63;
  const int lr = l & 15, lg = l >> 4;
  const int q0w = qchunk * 128 + w * 32;  // wave's 32 queries
  const float inv_tp = 0.08838834764831845f;  // 1/sqrt(2*64)

  const unsigned short* Kbase = Kb + (size_t)bh * Tn * 64;
  const unsigned short* Vbase = Vt + (size_t)bh * 64 * Tn;

  // Q fragments (B-operand of swapped QK^T): lane reads Q[q][d-chunk]
  const unsigned short* Qp = Q + ((size_t)bh * Tn + q0w) * 64;
  s16x8 qa[2][2];
#pragma unroll
  for (int qt = 0; qt < 2; ++qt) {
    qa[qt][0] = *(const s16x8*)(Qp + (qt * 16 + lr) * 64 + lg * 8);
    qa[qt][1] = *(const s16x8*)(Qp + (qt * 16 + lr) * 64 + 32 + lg * 8);
  }

  f32x4 o[2][4];  // O^T per q-tile: lane holds d = dt*16+lg*4+r, q = q0w+qt*16+lr
#pragma unroll
  for (int qt = 0; qt < 2; ++qt)
#pragma unroll
    for (int dt = 0; dt < 4; ++dt) o[qt][dt] = (f32x4){0.f, 0.f, 0.f, 0.f};
  float mrow[2] = {-1e30f, -1e30f}, lsum[2] = {0.f, 0.f};

  const int N = (q0w >> 5) + 1;  // tiles; last one is diagonal (masked)
  s16x8 kf0[2][2], kf1[2][2];
  s16x4 vf0[4][2], vf1[4][2];

  ATTN_LOAD(0, kf0, vf0);
  int kt = 0;
  for (; kt + 2 <= N; kt += 2) {
    ATTN_LOAD((kt + 1) * 32, kf1, vf1);
    ATTN_COMP(kt * 32, kf0, vf0, false);        // kt <= N-2: never diagonal
    if (kt + 2 < N) ATTN_LOAD((kt + 2) * 32, kf0, vf0);
    ATTN_COMP((kt + 1) * 32, kf1, vf1, kt + 1 == N - 1);
  }
  if (kt < N) ATTN_COMP(kt * 32, kf0, vf0, true);  // odd N: last tile

  // epilogue: normalize, gate, residual. lane: q = q0w+qt*16+lr, d = dt*16+lg*4+r
#pragma unroll
  for (int qt = 0; qt < 2; ++qt) {
    const float rinv = 1.f / lsum[qt];
    const int q = q0w + qt * 16 + lr;
#pragma unroll
    for (int dt = 0; dt < 4; ++dt) {
      const int colb = h * 64 + dt * 16 + lg * 4;
      const size_t idx2 = ((size_t)b * Tn + q) * Cn + colb;
      float4 xv = *(const float4*)(x + idx2);
      float4 gv = *(const float4*)(cm + b * 6144 + 2048 + colb);
      float4 ov;
      ov.x = xv.x + gv.x * o[qt][dt][0] * rinv;
      ov.y = xv.y + gv.y * o[qt][dt][1] * rinv;
      ov.z = xv.z + gv.z * o[qt][dt][2] * rinv;
      ov.w = xv.w + gv.w * o[qt][dt][3] * rinv;
      *(float4*)(x2 + idx2) = ov;
    }
  }
}

// ---------------- launch ----------------
extern "C" void kernel_launch(void* const* d_in, const int* in_sizes, int n_in,
                              void* d_out, int out_size, void* d_ws, size_t ws_size,
                              hipStream_t stream) {
  (void)in_sizes; (void)n_in; (void)out_size; (void)ws_size;
  const float* x = (const float*)d_in[0];
  const float* pe_cos = (const float*)d_in[1];
  const float* pe_sin = (const float*)d_in[2];
  const float* pe_scale = (const float*)d_in[3];
  const float* cc = (const float*)d_in[4];
  // d_in[5] = mask: causal, computed analytically
  const float* qkv_w = (const float*)d_in[6];
  const float* qkv_b = (const float*)d_in[7];
  const float* w1 = (const float*)d_in[8];
  const float* b1 = (const float*)d_in[9];
  const float* w2 = (const float*)d_in[10];
  const float* b2 = (const float*)d_in[11];
  const float* ada_w = (const float*)d_in[12];
  const float* ada_b = (const float*)d_in[13];
  float* out = (float*)d_out;
  char* ws = (char*)d_ws;

  unsigned short* qkvw_bf = (unsigned short*)(ws + 0);
  unsigned short* w1_bf = (unsigned short*)(ws + 6291456);
  unsigned short* w2_bf = (unsigned short*)(ws + 14680064);
  float* cm = (float*)(ws + 23068672);
  unsigned short* h1 = (unsigned short*)(ws + 23117824);   // reused as h2
  unsigned short* qkvb = (unsigned short*)(ws + 31506432); // reused (+Q) as ff1
  unsigned short* Qb = (unsigned short*)(ws + 56672256);
  unsigned short* Kb2 = (unsigned short*)(ws + 65060864);
  unsigned short* Vtb = (unsigned short*)(ws + 73449472);
  float* x2b = (float*)(ws + 81838080);
  unsigned short* ff1b = (unsigned short*)(ws + 31506432);
  // total ws use: 98,615,296 bytes

  cast_f32_bf16<<<3072, 256, 0, stream>>>(qkv_w, qkvw_bf);
  cast_f32_bf16<<<4096, 256, 0, stream>>>(w1, w1_bf);
  cast_f32_bf16<<<4096, 256, 0, stream>>>(w2, w2_bf);
  modulation<<<3072, 256, 0, stream>>>(cc, ada_w, ada_b, cm);
  ln_mod<<<4096, 256, 0, stream>>>(x, cm, h1, 0, 1024);
  gemm_bt<0><<<dim3(24, 32), 256, 0, stream>>>(h1, qkvw_bf, qkv_b, qkvb, nullptr, nullptr, nullptr, 4096, 3072, 1024);
  rope_pack<<<1024, 256, 0, stream>>>(qkvb, pe_cos, pe_sin, pe_scale, Qb, Kb2, Vtb);
  attn_kernel<<<512, 256, 0, stream>>>(Qb, Kb2, Vtb, x, cm, x2b);
  ln_mod<<<4096, 256, 0, stream>>>(x2b, cm, h1, 3072, 4096);
  gemm_bt<1><<<dim3(32, 32), 256, 0, stream>>>(h1, w1_bf, b1, ff1b, nullptr, nullptr, nullptr, 4096, 4096, 1024);
  gemm_bt<2><<<dim3(8, 32), 256, 0, stream>>>(ff1b, w2_bf, b2, nullptr, out, x2b, cm, 4096, 1024, 4096);
}